// Round 2
// baseline (2110.990 us; speedup 1.0000x reference)
//
#include <hip/hip_runtime.h>

typedef __attribute__((ext_vector_type(8))) short bf16x8;
typedef __attribute__((ext_vector_type(4))) float f32x4;
typedef unsigned short u16;

__device__ __forceinline__ u16 f2bf(float f) {
  union { float f; unsigned u; } v; v.f = f;
  unsigned r = v.u + 0x7fffu + ((v.u >> 16) & 1u);
  return (u16)(r >> 16);
}
__device__ __forceinline__ float bf2f(u16 s) {
  union { unsigned u; float f; } v; v.u = ((unsigned)s) << 16;
  return v.f;
}
__device__ __forceinline__ f32x4 mfma_bf16(bf16x8 a, bf16x8 b, f32x4 c) {
  return __builtin_amdgcn_mfma_f32_16x16x32_bf16(a, b, c, 0, 0, 0);
}

// split helpers
__device__ __forceinline__ void split2(float x, u16& h, u16& l) {
  h = f2bf(x);
  l = f2bf(x - bf2f(h));
}
__device__ __forceinline__ void split3(float x, u16& h, u16& m, u16& l) {
  h = f2bf(x);
  float r = x - bf2f(h);
  m = f2bf(r);
  l = f2bf(r - bf2f(m));
}

// ---------------- LayerNorm (fp32), one wave per row ----------------
__global__ __launch_bounds__(256) void ln_kernel(
    const float* __restrict__ x, const float* __restrict__ gamma,
    const float* __restrict__ beta, float* __restrict__ o, int rows, int C) {
  int wid = threadIdx.x >> 6, lane = threadIdx.x & 63;
  int row = blockIdx.x * 4 + wid;
  if (row >= rows) return;
  const float* xr = x + (size_t)row * C;
  float s = 0.f, s2 = 0.f;
  for (int c = lane; c < C; c += 64) { float v = xr[c]; s += v; s2 += v * v; }
  #pragma unroll
  for (int off = 32; off >= 1; off >>= 1) {
    s += __shfl_xor(s, off);
    s2 += __shfl_xor(s2, off);
  }
  float m = s / C;
  float var = s2 / C - m * m;
  float rs = rsqrtf(var + 1e-5f);
  float* orow = o + (size_t)row * C;
  for (int c = lane; c < C; c += 64) orow[c] = (xr[c] - m) * rs * gamma[c] + beta[c];
}

// ------- Dense GEMM, fp32-accurate via 3-way bf16 split: O = act(A @ W^T + bias) -------
// A: [M,K] fp32 row-major.  W: [N,K] fp32 row-major.  BM=BN=64, BK=32, 256 thr.
template <int ACT, int ACC>   // ACT: 0 none, 1 relu, 2 sigmoid.  ACC: O += vs O =
__global__ __launch_bounds__(256) void gemm_kernel(
    const float* __restrict__ A, const float* __restrict__ W,
    const float* __restrict__ bias, float* __restrict__ O,
    int M, int N, int K) {
  __shared__ __align__(16) u16 a_h[64][40], a_m[64][40], a_l[64][40];
  __shared__ __align__(16) u16 w_h[64][40], w_m[64][40], w_l[64][40];
  const int n0 = blockIdx.x * 64, m0 = blockIdx.y * 64;
  const int t = threadIdx.x;
  const int wid = t >> 6, lane = t & 63;
  const int cl = lane & 15, cg = lane >> 4;
  const int lrow = t >> 2, lq = t & 3;
  f32x4 acc[4] = {};
  for (int k0 = 0; k0 < K; k0 += 32) {
    {
      const float* asrc = A + (size_t)(m0 + lrow) * K + k0 + lq * 8;
      float4 a0 = ((const float4*)asrc)[0];
      float4 a1 = ((const float4*)asrc)[1];
      float av[8] = {a0.x, a0.y, a0.z, a0.w, a1.x, a1.y, a1.z, a1.w};
      union { u16 s[8]; uint4 u; } ph, pm, pl;
      #pragma unroll
      for (int j = 0; j < 8; j++) split3(av[j], ph.s[j], pm.s[j], pl.s[j]);
      *(uint4*)&a_h[lrow][lq * 8] = ph.u;
      *(uint4*)&a_m[lrow][lq * 8] = pm.u;
      *(uint4*)&a_l[lrow][lq * 8] = pl.u;
      const float* wsrc = W + (size_t)(n0 + lrow) * K + k0 + lq * 8;
      float4 w0 = ((const float4*)wsrc)[0];
      float4 w1 = ((const float4*)wsrc)[1];
      float wv[8] = {w0.x, w0.y, w0.z, w0.w, w1.x, w1.y, w1.z, w1.w};
      #pragma unroll
      for (int j = 0; j < 8; j++) split3(wv[j], ph.s[j], pm.s[j], pl.s[j]);
      *(uint4*)&w_h[lrow][lq * 8] = ph.u;
      *(uint4*)&w_m[lrow][lq * 8] = pm.u;
      *(uint4*)&w_l[lrow][lq * 8] = pl.u;
    }
    __syncthreads();
    bf16x8 ah = *(const bf16x8*)&a_h[wid * 16 + cl][cg * 8];
    bf16x8 am = *(const bf16x8*)&a_m[wid * 16 + cl][cg * 8];
    bf16x8 al = *(const bf16x8*)&a_l[wid * 16 + cl][cg * 8];
    #pragma unroll
    for (int nt = 0; nt < 4; nt++) {
      bf16x8 bh = *(const bf16x8*)&w_h[nt * 16 + cl][cg * 8];
      bf16x8 bm = *(const bf16x8*)&w_m[nt * 16 + cl][cg * 8];
      bf16x8 bl = *(const bf16x8*)&w_l[nt * 16 + cl][cg * 8];
      acc[nt] = mfma_bf16(ah, bh, acc[nt]);
      acc[nt] = mfma_bf16(ah, bm, acc[nt]);
      acc[nt] = mfma_bf16(am, bh, acc[nt]);
      acc[nt] = mfma_bf16(ah, bl, acc[nt]);
      acc[nt] = mfma_bf16(al, bh, acc[nt]);
      acc[nt] = mfma_bf16(am, bm, acc[nt]);
    }
    __syncthreads();
  }
  #pragma unroll
  for (int nt = 0; nt < 4; nt++) {
    #pragma unroll
    for (int i = 0; i < 4; i++) {
      int r = m0 + wid * 16 + cg * 4 + i;
      int c = n0 + nt * 16 + cl;
      float v = acc[nt][i];
      if (bias) v += bias[c];
      if (ACT == 1) v = fmaxf(v, 0.f);
      if (ACT == 2) v = 1.f / (1.f + __expf(-v));
      size_t oi = (size_t)r * N + c;
      if (ACC) O[oi] += v; else O[oi] = v;
    }
  }
}

// ------- Fused LN(z) + z@w_b^T -> bmat, 2-way split GEMM, fp32 (or bf16) store -------
// grid: B*N*(N/64) = 8192 blocks, 256 threads. Tile: 64 rows (j) x 96 ch, K=128.
template <int OUT32>
__global__ __launch_bounds__(256) void zbmat_kernel(
    const float* __restrict__ z, const float* __restrict__ gamma,
    const float* __restrict__ beta, const float* __restrict__ wb,
    const float* __restrict__ bbias, void* __restrict__ bmat_out) {
  __shared__ __align__(16) char smem[87040];
  u16 (*w_h)[136] = (u16(*)[136])smem;             // 96*136*2 = 26112
  u16 (*w_l)[136] = (u16(*)[136])(smem + 26112);   // 26112
  u16 (*a_h)[136] = (u16(*)[136])(smem + 52224);   // 17408
  u16 (*a_l)[136] = (u16(*)[136])(smem + 69632);   // 17408
  float (*c_f)[72] = (float(*)[72])(smem + 52224); // aliases a planes (27648 <= 34816)
  const int bid = blockIdx.x;
  const int b = bid >> 12;
  const int rem = bid & 4095;
  const int i = rem >> 3;
  const int jt = rem & 7;
  const int t = threadIdx.x;
  // stage w_b split
  for (int idx = t; idx < 96 * 128; idx += 256) {
    u16 h, l; split2(wb[idx], h, l);
    w_h[idx >> 7][idx & 127] = h;
    w_l[idx >> 7][idx & 127] = l;
  }
  // load 64 z rows: thread -> (row r, quarter q) holding 32 channels
  const int r = t >> 2, q = t & 3;
  const float* zr = z + ((size_t)(b * 512 + i) * 512 + (jt * 64 + r)) * 128 + q * 32;
  float4 v[8];
  float s = 0.f, s2 = 0.f;
  #pragma unroll
  for (int ii = 0; ii < 8; ii++) {
    v[ii] = ((const float4*)zr)[ii];
    s += v[ii].x + v[ii].y + v[ii].z + v[ii].w;
    s2 += v[ii].x * v[ii].x + v[ii].y * v[ii].y + v[ii].z * v[ii].z + v[ii].w * v[ii].w;
  }
  s += __shfl_xor(s, 1); s2 += __shfl_xor(s2, 1);
  s += __shfl_xor(s, 2); s2 += __shfl_xor(s2, 2);
  const float m = s * (1.f / 128.f);
  const float var = s2 * (1.f / 128.f) - m * m;
  const float rs = rsqrtf(var + 1e-5f);
  const int cq = q * 32;
  #pragma unroll
  for (int st = 0; st < 4; st++) {
    float4 x0 = v[2 * st], x1 = v[2 * st + 1];
    float xv[8] = {x0.x, x0.y, x0.z, x0.w, x1.x, x1.y, x1.z, x1.w};
    union { u16 s[8]; uint4 u; } ph, pl;
    #pragma unroll
    for (int j = 0; j < 8; j++) {
      float g = gamma[cq + st * 8 + j], be = beta[cq + st * 8 + j];
      split2((xv[j] - m) * rs * g + be, ph.s[j], pl.s[j]);
    }
    *(uint4*)&a_h[r][cq + st * 8] = ph.u;
    *(uint4*)&a_l[r][cq + st * 8] = pl.u;
  }
  __syncthreads();
  // MFMA: each wave = one 16-row M tile, 6 N tiles, K=128 (4 steps), 2-way split
  const int wid = t >> 6, lane = t & 63;
  const int cl = lane & 15, cg = lane >> 4;
  const int arow = wid * 16 + cl;
  f32x4 acc[6] = {};
  #pragma unroll
  for (int ks = 0; ks < 4; ks++) {
    bf16x8 ah = *(const bf16x8*)&a_h[arow][ks * 32 + cg * 8];
    bf16x8 al = *(const bf16x8*)&a_l[arow][ks * 32 + cg * 8];
    #pragma unroll
    for (int nt = 0; nt < 6; nt++) {
      bf16x8 bh = *(const bf16x8*)&w_h[nt * 16 + cl][ks * 32 + cg * 8];
      bf16x8 bl = *(const bf16x8*)&w_l[nt * 16 + cl][ks * 32 + cg * 8];
      acc[nt] = mfma_bf16(ah, bh, acc[nt]);
      acc[nt] = mfma_bf16(ah, bl, acc[nt]);
      acc[nt] = mfma_bf16(al, bh, acc[nt]);
    }
  }
  __syncthreads();  // all waves done reading a planes before aliasing as c_f
  #pragma unroll
  for (int nt = 0; nt < 6; nt++) {
    #pragma unroll
    for (int ii = 0; ii < 4; ii++) {
      int ch = nt * 16 + cl;
      int jl = wid * 16 + cg * 4 + ii;
      c_f[ch][jl] = acc[nt][ii] + bbias[ch];
    }
  }
  __syncthreads();
  if (OUT32) {
    float* bm = (float*)bmat_out;
    #pragma unroll
    for (int ii = 0; ii < 6; ii++) {
      int idx = t + 256 * ii;                 // 1536 float4 chunks
      int ch = idx >> 4, pos = (idx & 15) * 4;
      float4 val = *(const float4*)&c_f[ch][pos];
      *(float4*)&bm[(((size_t)(b * 96 + ch) * 512 + i) * 512 + jt * 64 + pos)] = val;
    }
  } else {
    u16* bm = (u16*)bmat_out;
    #pragma unroll
    for (int ii = 0; ii < 6; ii++) {
      int idx = t + 256 * ii;
      int ch = idx >> 4, pos = (idx & 15) * 4;
      ushort4 pk;
      pk.x = f2bf(c_f[ch][pos + 0]); pk.y = f2bf(c_f[ch][pos + 1]);
      pk.z = f2bf(c_f[ch][pos + 2]); pk.w = f2bf(c_f[ch][pos + 3]);
      *(ushort4*)&bm[(((size_t)(b * 96 + ch) * 512 + i) * 512 + jt * 64 + pos)] = pk;
    }
  }
}

// ---------------- Fused attention (one layer), 2-way split precision ----------------
// grid: B*H*(N/32) = 384 blocks, 128 threads (2 waves). Wave -> 16 q rows.
template <int B32>
__global__ __launch_bounds__(128) void attn_kernel(
    const float* __restrict__ qkv, const void* __restrict__ bmat,
    const int* __restrict__ maskp, const float* __restrict__ gate,
    float* __restrict__ ybuf, int layer) {
  __shared__ __align__(16) u16 vT_h[32][520];
  __shared__ __align__(16) u16 vT_l[32][520];
  __shared__ __align__(16) u16 pst_h[2][16][32];
  __shared__ __align__(16) u16 pst_l[2][16][32];
  const int bid = blockIdx.x;
  const int qb = bid & 15;
  const int h = (bid >> 4) % 12;
  const int b = bid / 192;
  const int q0 = qb * 32;
  const int t = threadIdx.x;
  const int wid = t >> 6;
  const int lane = t & 63;
  const int cl = lane & 15, cg = lane >> 4;

  // stage V^T split
  for (int idx = t; idx < 512 * 8; idx += 128) {
    int k = idx >> 3, c4 = (idx & 7) << 2;
    const float* vp = qkv + (size_t)(b * 512 + k) * 1152 + h * 96 + 64 + c4;
    float4 vv = *(const float4*)vp;
    float va[4] = {vv.x, vv.y, vv.z, vv.w};
    #pragma unroll
    for (int j = 0; j < 4; j++) {
      u16 hh, ll; split2(va[j], hh, ll);
      vT_h[c4 + j][k] = hh;
      vT_l[c4 + j][k] = ll;
    }
  }

  // Q fragment (scaled by HD^-0.5), split
  const int qrow = q0 + wid * 16 + cl;
  const float* qp = qkv + (size_t)(b * 512 + qrow) * 1152 + h * 96 + cg * 8;
  float4 qv0 = ((const float4*)qp)[0];
  float4 qv1 = ((const float4*)qp)[1];
  const float qs = 0.17677669529663687f;
  float qa[8] = {qv0.x, qv0.y, qv0.z, qv0.w, qv1.x, qv1.y, qv1.z, qv1.w};
  union { u16 s[8]; bf16x8 v; } qh, ql;
  #pragma unroll
  for (int j = 0; j < 8; j++) split2(qa[j] * qs, qh.s[j], ql.s[j]);

  __syncthreads();

  const f32x4 zero4 = {0.f, 0.f, 0.f, 0.f};
  f32x4 sc[32];
  #pragma unroll
  for (int nt = 0; nt < 32; nt++) {
    int kk = nt * 16 + cl;
    const float* kp = qkv + (size_t)(b * 512 + kk) * 1152 + h * 96 + 32 + cg * 8;
    float4 k0 = ((const float4*)kp)[0];
    float4 k1 = ((const float4*)kp)[1];
    float ka[8] = {k0.x, k0.y, k0.z, k0.w, k1.x, k1.y, k1.z, k1.w};
    union { u16 s[8]; bf16x8 v; } kh, kl;
    #pragma unroll
    for (int j = 0; j < 8; j++) split2(ka[j], kh.s[j], kl.s[j]);
    f32x4 a = mfma_bf16(qh.v, kh.v, zero4);
    a = mfma_bf16(qh.v, kl.v, a);
    a = mfma_bf16(ql.v, kh.v, a);
    sc[nt] = a;
  }

  // bias + mask
  const size_t bc = (size_t)(b * 96 + layer * 12 + h);
  #pragma unroll
  for (int nt = 0; nt < 32; nt++) {
    int kk = nt * 16 + cl;
    int mk = maskp[b * 512 + kk];
    #pragma unroll
    for (int i2 = 0; i2 < 4; i2++) {
      int qq = q0 + wid * 16 + cg * 4 + i2;
      float bias = B32 ? ((const float*)bmat)[(bc * 512 + qq) * 512 + kk]
                       : bf2f(((const u16*)bmat)[(bc * 512 + qq) * 512 + kk]);
      float vv = sc[nt][i2] + bias;
      sc[nt][i2] = (mk == 0) ? -1e9f : vv;
    }
  }

  // softmax per row (row lives in 16 lanes with same cg)
  float inv[4];
  #pragma unroll
  for (int i2 = 0; i2 < 4; i2++) {
    float mx = -3e38f;
    #pragma unroll
    for (int nt = 0; nt < 32; nt++) mx = fmaxf(mx, sc[nt][i2]);
    mx = fmaxf(mx, __shfl_xor(mx, 1));
    mx = fmaxf(mx, __shfl_xor(mx, 2));
    mx = fmaxf(mx, __shfl_xor(mx, 4));
    mx = fmaxf(mx, __shfl_xor(mx, 8));
    float ss = 0.f;
    #pragma unroll
    for (int nt = 0; nt < 32; nt++) {
      float p = __expf(sc[nt][i2] - mx);
      sc[nt][i2] = p;
      ss += p;
    }
    ss += __shfl_xor(ss, 1);
    ss += __shfl_xor(ss, 2);
    ss += __shfl_xor(ss, 4);
    ss += __shfl_xor(ss, 8);
    inv[i2] = 1.f / ss;
  }

  // PV: 16 K-steps of 32, split P and V
  f32x4 yacc[2] = {};
  for (int ks = 0; ks < 16; ks++) {
    #pragma unroll
    for (int half = 0; half < 2; half++) {
      int nt = ks * 2 + half;
      #pragma unroll
      for (int i2 = 0; i2 < 4; i2++) {
        u16 hh, ll; split2(sc[nt][i2] * inv[i2], hh, ll);
        pst_h[wid][cg * 4 + i2][half * 16 + cl] = hh;
        pst_l[wid][cg * 4 + i2][half * 16 + cl] = ll;
      }
    }
    __syncthreads();
    bf16x8 ph = *(const bf16x8*)&pst_h[wid][cl][cg * 8];
    bf16x8 pl = *(const bf16x8*)&pst_l[wid][cl][cg * 8];
    #pragma unroll
    for (int nt2 = 0; nt2 < 2; nt2++) {
      bf16x8 vh = *(const bf16x8*)&vT_h[nt2 * 16 + cl][ks * 32 + cg * 8];
      bf16x8 vl = *(const bf16x8*)&vT_l[nt2 * 16 + cl][ks * 32 + cg * 8];
      yacc[nt2] = mfma_bf16(ph, vh, yacc[nt2]);
      yacc[nt2] = mfma_bf16(ph, vl, yacc[nt2]);
      yacc[nt2] = mfma_bf16(pl, vh, yacc[nt2]);
    }
    __syncthreads();
  }

  // epilogue: y_gated = gate * y
  #pragma unroll
  for (int nt2 = 0; nt2 < 2; nt2++) {
    #pragma unroll
    for (int i2 = 0; i2 < 4; i2++) {
      int qq = q0 + wid * 16 + cg * 4 + i2;
      int c = nt2 * 16 + cl;
      size_t oi = (size_t)(b * 512 + qq) * 384 + h * 32 + c;
      ybuf[oi] = yacc[nt2][i2] * gate[oi];
    }
  }
}

// ---------------- small fp32 matvec GEMM: thread per (row, out) ----------------
template <int INRELU, int ACC>
__global__ __launch_bounds__(256) void matvec_kernel(
    const float* __restrict__ A, const float* __restrict__ W,
    const float* __restrict__ bias, float* __restrict__ O,
    int M, int N, int K, int Npad) {
  int idx = blockIdx.x * 256 + threadIdx.x;
  int r = idx / Npad, n = idx % Npad;
  if (r >= M || n >= N) return;
  const float* a = A + (size_t)r * K;
  const float* w = W + (size_t)n * K;
  float s = bias[n];
  for (int k = 0; k < K; k++) {
    float v = a[k];
    if (INRELU) v = fmaxf(v, 0.f);
    s += v * w[k];
  }
  size_t oi = (size_t)r * N + n;
  if (ACC) O[oi] += s; else O[oi] = s;
}

// ---------------- angle normalization ----------------
__global__ __launch_bounds__(256) void norm_angles_kernel(
    const float* __restrict__ ang, float* __restrict__ o_ang, float* __restrict__ o_un) {
  int idx = blockIdx.x * 256 + threadIdx.x;
  if (idx >= 2 * 512 * 7) return;
  float s0 = ang[idx * 2], s1 = ang[idx * 2 + 1];
  o_un[idx * 2] = s0; o_un[idx * 2 + 1] = s1;
  float d = sqrtf(fmaxf(s0 * s0 + s1 * s1, 1e-8f));
  o_ang[idx * 2] = s0 / d; o_ang[idx * 2 + 1] = s1 / d;
}

// ---------------- make_rigid ----------------
__global__ __launch_bounds__(256) void rigid_kernel(
    const float* __restrict__ bb, float* __restrict__ rbb, float* __restrict__ o_bb4) {
  int idx = blockIdx.x * 256 + threadIdx.x;
  if (idx >= 1024) return;
  const float* p = bb + (size_t)idx * 9;
  float nx = p[0] - p[3], ny = p[1] - p[4], nz = p[2] - p[5];
  float cx = p[6] - p[3], cy = p[7] - p[4], cz = p[8] - p[5];
  const float eps = 1e-7f;
  float nrm = sqrtf(eps + cx * cx + cy * cy);
  float s1 = -cy / nrm, c1 = cx / nrm;
  float nrm2 = sqrtf(eps + cx * cx + cy * cy + cz * cz);
  float s2 = cz / nrm2, c2 = sqrtf(cx * cx + cy * cy) / nrm2;
  float Rc[9] = { c2 * c1, -c2 * s1, s2,
                  s1,      c1,       0.f,
                  -s2 * c1, s2 * s1, c2 };
  float n2y = Rc[3] * nx + Rc[4] * ny + Rc[5] * nz;
  float n2z = Rc[6] * nx + Rc[7] * ny + Rc[8] * nz;
  float nrm3 = sqrtf(eps + n2y * n2y + n2z * n2z);
  float sn = -n2z / nrm3, cn = n2y / nrm3;
  float Rm[9];
  Rm[0] = Rc[0]; Rm[1] = Rc[1]; Rm[2] = Rc[2];
  Rm[3] = cn * Rc[3] - sn * Rc[6];
  Rm[4] = cn * Rc[4] - sn * Rc[7];
  Rm[5] = cn * Rc[5] - sn * Rc[8];
  Rm[6] = sn * Rc[3] + cn * Rc[6];
  Rm[7] = sn * Rc[4] + cn * Rc[7];
  Rm[8] = sn * Rc[5] + cn * Rc[8];
  float R[9] = { Rm[0], Rm[3], Rm[6],
                 Rm[1], Rm[4], Rm[7],
                 Rm[2], Rm[5], Rm[8] };
  float t0 = p[3] * 10.f, t1 = p[4] * 10.f, t2 = p[5] * 10.f;
  #pragma unroll
  for (int i = 0; i < 9; i++) rbb[idx * 12 + i] = R[i];
  rbb[idx * 12 + 9] = t0; rbb[idx * 12 + 10] = t1; rbb[idx * 12 + 11] = t2;
  float* o = o_bb4 + (size_t)idx * 16;
  o[0] = R[0]; o[1] = R[1]; o[2] = R[2]; o[3] = t0;
  o[4] = R[3]; o[5] = R[4]; o[6] = R[5]; o[7] = t1;
  o[8] = R[6]; o[9] = R[7]; o[10] = R[8]; o[11] = t2;
  o[12] = 0.f; o[13] = 0.f; o[14] = 0.f; o[15] = 1.f;
}

__device__ __forceinline__ void m3m(float* o, const float* a, const float* b) {
  #pragma unroll
  for (int i = 0; i < 3; i++)
    #pragma unroll
    for (int j = 0; j < 3; j++)
      o[i * 3 + j] = a[i * 3 + 0] * b[0 * 3 + j] + a[i * 3 + 1] * b[1 * 3 + j] + a[i * 3 + 2] * b[2 * 3 + j];
}
__device__ __forceinline__ void m3v(float* o, const float* a, const float* v) {
  #pragma unroll
  for (int i = 0; i < 3; i++)
    o[i] = a[i * 3 + 0] * v[0] + a[i * 3 + 1] * v[1] + a[i * 3 + 2] * v[2];
}

// ---------------- frames + atoms ----------------
__global__ __launch_bounds__(256) void frames_kernel(
    const int* __restrict__ aatype, const float* __restrict__ angles,
    const float* __restrict__ rbb, const float* __restrict__ deff,
    const int* __restrict__ gidx, const float* __restrict__ amask,
    const float* __restrict__ lit, float* __restrict__ o_rg4, float* __restrict__ o_pred) {
  int idx = blockIdx.x * 256 + threadIdx.x;
  if (idx >= 1024) return;
  int aa = aatype[idx];
  float Rb[9], tb[3];
  #pragma unroll
  for (int i = 0; i < 9; i++) Rb[i] = rbb[idx * 12 + i];
  tb[0] = rbb[idx * 12 + 9]; tb[1] = rbb[idx * 12 + 10]; tb[2] = rbb[idx * 12 + 11];
  float Rf[8][9], tf[8][3];
  for (int g = 0; g < 8; g++) {
    const float* d4 = deff + ((size_t)aa * 8 + g) * 16;
    float sa = 0.f, ca = 1.f;
    if (g > 0) {
      sa = angles[(idx * 7 + g - 1) * 2 + 0];
      ca = angles[(idx * 7 + g - 1) * 2 + 1];
    }
    #pragma unroll
    for (int i = 0; i < 3; i++) {
      float d0 = d4[i * 4 + 0], d1 = d4[i * 4 + 1], d2 = d4[i * 4 + 2];
      Rf[g][i * 3 + 0] = d0;
      Rf[g][i * 3 + 1] = d1 * ca + d2 * sa;
      Rf[g][i * 3 + 2] = -d1 * sa + d2 * ca;
      tf[g][i] = d4[i * 4 + 3];
    }
  }
  float Rall[8][9], tall[8][3];
  for (int g = 0; g < 5; g++) {
    #pragma unroll
    for (int i = 0; i < 9; i++) Rall[g][i] = Rf[g][i];
    #pragma unroll
    for (int i = 0; i < 3; i++) tall[g][i] = tf[g][i];
  }
  m3m(Rall[5], Rf[4], Rf[5]); m3v(tall[5], Rf[4], tf[5]);
  tall[5][0] += tf[4][0]; tall[5][1] += tf[4][1]; tall[5][2] += tf[4][2];
  m3m(Rall[6], Rall[5], Rf[6]); m3v(tall[6], Rall[5], tf[6]);
  tall[6][0] += tall[5][0]; tall[6][1] += tall[5][1]; tall[6][2] += tall[5][2];
  m3m(Rall[7], Rall[6], Rf[7]); m3v(tall[7], Rall[6], tf[7]);
  tall[7][0] += tall[6][0]; tall[7][1] += tall[6][1]; tall[7][2] += tall[6][2];
  float RG[8][9], TG[8][3];
  for (int g = 0; g < 8; g++) {
    m3m(RG[g], Rb, Rall[g]);
    m3v(TG[g], Rb, tall[g]);
    TG[g][0] += tb[0]; TG[g][1] += tb[1]; TG[g][2] += tb[2];
    float* o = o_rg4 + ((size_t)idx * 8 + g) * 16;
    o[0] = RG[g][0]; o[1] = RG[g][1]; o[2] = RG[g][2]; o[3] = TG[g][0];
    o[4] = RG[g][3]; o[5] = RG[g][4]; o[6] = RG[g][5]; o[7] = TG[g][1];
    o[8] = RG[g][6]; o[9] = RG[g][7]; o[10] = RG[g][8]; o[11] = TG[g][2];
    o[12] = 0.f; o[13] = 0.f; o[14] = 0.f; o[15] = 1.f;
  }
  for (int a = 0; a < 14; a++) {
    int gi = gidx[aa * 14 + a];
    const float* lp = lit + ((size_t)aa * 14 + a) * 3;
    float mk = amask[aa * 14 + a];
    float px = RG[gi][0] * lp[0] + RG[gi][1] * lp[1] + RG[gi][2] * lp[2] + TG[gi][0];
    float py = RG[gi][3] * lp[0] + RG[gi][4] * lp[1] + RG[gi][5] * lp[2] + TG[gi][1];
    float pz = RG[gi][6] * lp[0] + RG[gi][7] * lp[1] + RG[gi][8] * lp[2] + TG[gi][2];
    float* op = o_pred + ((size_t)idx * 14 + a) * 3;
    op[0] = px * mk; op[1] = py * mk; op[2] = pz * mk;
  }
}

__global__ __launch_bounds__(256) void copy_kernel(const float4* __restrict__ s, float4* __restrict__ d) {
  int i = blockIdx.x * 256 + threadIdx.x;
  d[i] = s[i];
}

extern "C" void kernel_launch(void* const* d_in, const int* in_sizes, int n_in,
                              void* d_out, int out_size, void* d_ws, size_t ws_size,
                              hipStream_t stream) {
  (void)in_sizes; (void)n_in; (void)out_size;
  const float* s_in    = (const float*)d_in[0];
  const float* z_in    = (const float*)d_in[1];
  const int*   aatype  = (const int*)d_in[2];
  const int*   maskp   = (const int*)d_in[3];
  const float* ln_s_g  = (const float*)d_in[4];
  const float* ln_s_b  = (const float*)d_in[5];
  const float* ln_z_g  = (const float*)d_in[6];
  const float* ln_z_b  = (const float*)d_in[7];
  const float* w_in    = (const float*)d_in[8];
  const float* b_in    = (const float*)d_in[9];
  const float* w_b     = (const float*)d_in[10];
  const float* b_b     = (const float*)d_in[11];
  const float* attn_ln_g = (const float*)d_in[12];
  const float* attn_ln_b = (const float*)d_in[13];
  const float* attn_wqkv = (const float*)d_in[14];
  const float* attn_wo   = (const float*)d_in[15];
  const float* attn_bo   = (const float*)d_in[16];
  const float* attn_wg   = (const float*)d_in[17];
  const float* attn_bg   = (const float*)d_in[18];
  const float* tr_ln_g   = (const float*)d_in[19];
  const float* tr_ln_b   = (const float*)d_in[20];
  const float* tr_w1     = (const float*)d_in[21];
  const float* tr_b1     = (const float*)d_in[22];
  const float* tr_w2     = (const float*)d_in[23];
  const float* tr_b2     = (const float*)d_in[24];
  const float* w_bb      = (const float*)d_in[25];
  const float* b_bb      = (const float*)d_in[26];
  const float* ar_win    = (const float*)d_in[27];
  const float* ar_bin    = (const float*)d_in[28];
  const float* ar_winit  = (const float*)d_in[29];
  const float* ar_binit  = (const float*)d_in[30];
  const float* ar_w1     = (const float*)d_in[31];
  const float* ar_b1     = (const float*)d_in[32];
  const float* ar_w2     = (const float*)d_in[33];
  const float* ar_b2     = (const float*)d_in[34];
  const float* ar_wout   = (const float*)d_in[35];
  const float* ar_bout   = (const float*)d_in[36];
  const float* def_frames= (const float*)d_in[37];
  const int*   group_idx = (const int*)d_in[38];
  const float* atom_mask = (const float*)d_in[39];
  const float* lit_pos   = (const float*)d_in[40];

  char* ws = (char*)d_ws;
  const size_t small_bytes = 16 * 1024 * 1024;               // all non-bmat buffers ~14.3MB
  const size_t bmat32_bytes = (size_t)201326592;
  const bool bm32 = ws_size >= bmat32_bytes + small_bytes;
  const size_t bmat_bytes = bm32 ? bmat32_bytes : (size_t)100663296;

  char* p = ws;
  void* bmat = (void*)p;              p += bmat_bytes;
  float* s_init = (float*)p;          p += 1572864;
  float* s_cur  = (float*)p;          p += 1572864;
  float* xn     = (float*)p;          p += 1572864;
  float* qkv    = (float*)p;          p += 4718592;
  float* gbuf   = (float*)p;          p += 1572864;
  float* ybuf   = (float*)p;          p += 1572864;
  float* h1buf  = (float*)p;          p += 1572864;
  float* abuf   = (float*)p;          p += 524288;
  float* htmp   = (float*)p;          p += 524288;
  float* angraw = (float*)p;          p += 57344;
  float* bbbuf  = (float*)p;          p += 36864;
  float* rbbbuf = (float*)p;          p += 49152;

  float* out    = (float*)d_out;
  float* o_ang  = out;
  float* o_un   = out + 14336;
  float* o_bb4  = out + 28672;
  float* o_rg4  = out + 45056;
  float* o_pred = out + 176128;
  float* o_s    = out + 219136;

  // s = LN(s); s_init = s
  ln_kernel<<<256, 256, 0, stream>>>(s_in, ln_s_g, ln_s_b, s_init, 1024, 384);
  // s = lin(s_init, w_in, b_in)
  gemm_kernel<0, 0><<<dim3(6, 16), 256, 0, stream>>>(s_init, w_in, b_in, s_cur, 1024, 384, 384);
  // bmat from z
  if (bm32)
    zbmat_kernel<1><<<8192, 256, 0, stream>>>(z_in, ln_z_g, ln_z_b, w_b, b_b, bmat);
  else
    zbmat_kernel<0><<<8192, 256, 0, stream>>>(z_in, ln_z_g, ln_z_b, w_b, b_b, bmat);

  for (int l = 0; l < 8; ++l) {
    ln_kernel<<<256, 256, 0, stream>>>(s_cur, attn_ln_g + l * 384, attn_ln_b + l * 384, xn, 1024, 384);
    gemm_kernel<0, 0><<<dim3(18, 16), 256, 0, stream>>>(
        xn, attn_wqkv + (size_t)l * 442368, (const float*)nullptr, qkv, 1024, 1152, 384);
    gemm_kernel<2, 0><<<dim3(6, 16), 256, 0, stream>>>(
        xn, attn_wg + (size_t)l * 147456, attn_bg + l * 384, gbuf, 1024, 384, 384);
    if (bm32)
      attn_kernel<1><<<384, 128, 0, stream>>>(qkv, bmat, maskp, gbuf, ybuf, l);
    else
      attn_kernel<0><<<384, 128, 0, stream>>>(qkv, bmat, maskp, gbuf, ybuf, l);
    gemm_kernel<0, 1><<<dim3(6, 16), 256, 0, stream>>>(
        ybuf, attn_wo + (size_t)l * 147456, attn_bo + l * 384, s_cur, 1024, 384, 384);
    ln_kernel<<<256, 256, 0, stream>>>(s_cur, tr_ln_g + l * 384, tr_ln_b + l * 384, xn, 1024, 384);
    gemm_kernel<1, 0><<<dim3(6, 16), 256, 0, stream>>>(
        xn, tr_w1 + (size_t)l * 147456, tr_b1 + l * 384, h1buf, 1024, 384, 384);
    gemm_kernel<0, 1><<<dim3(6, 16), 256, 0, stream>>>(
        h1buf, tr_w2 + (size_t)l * 147456, tr_b2 + l * 384, s_cur, 1024, 384, 384);
  }

  // angle resnet (fp32 path)
  matvec_kernel<1, 0><<<512, 256, 0, stream>>>(s_cur, ar_win, ar_bin, abuf, 1024, 128, 384, 128);
  matvec_kernel<1, 1><<<512, 256, 0, stream>>>(s_init, ar_winit, ar_binit, abuf, 1024, 128, 384, 128);
  for (int j = 0; j < 2; ++j) {
    matvec_kernel<1, 0><<<512, 256, 0, stream>>>(abuf, ar_w1 + j * 16384, ar_b1 + j * 128, htmp, 1024, 128, 128, 128);
    matvec_kernel<1, 1><<<512, 256, 0, stream>>>(htmp, ar_w2 + j * 16384, ar_b2 + j * 128, abuf, 1024, 128, 128, 128);
  }
  matvec_kernel<1, 0><<<64, 256, 0, stream>>>(abuf, ar_wout, ar_bout, angraw, 1024, 14, 128, 16);
  norm_angles_kernel<<<28, 256, 0, stream>>>(angraw, o_ang, o_un);

  // backbone rigid
  matvec_kernel<0, 0><<<64, 256, 0, stream>>>(s_cur, w_bb, b_bb, bbbuf, 1024, 9, 384, 16);
  rigid_kernel<<<4, 256, 0, stream>>>(bbbuf, rbbbuf, o_bb4);
  frames_kernel<<<4, 256, 0, stream>>>(aatype, o_ang, rbbbuf, def_frames, group_idx,
                                       atom_mask, lit_pos, o_rg4, o_pred);
  copy_kernel<<<384, 256, 0, stream>>>((const float4*)s_cur, (float4*)o_s);
}

// Round 3
// 1379.091 us; speedup vs baseline: 1.5307x; 1.5307x over previous
//
#include <hip/hip_runtime.h>

typedef __attribute__((ext_vector_type(8))) short bf16x8;
typedef __attribute__((ext_vector_type(4))) float f32x4;
typedef unsigned short u16;

__device__ __forceinline__ u16 f2bf(float f) {
  union { float f; unsigned u; } v; v.f = f;
  unsigned r = v.u + 0x7fffu + ((v.u >> 16) & 1u);
  return (u16)(r >> 16);
}
__device__ __forceinline__ float bf2f(u16 s) {
  union { unsigned u; float f; } v; v.u = ((unsigned)s) << 16;
  return v.f;
}
__device__ __forceinline__ f32x4 mfma_bf16(bf16x8 a, bf16x8 b, f32x4 c) {
  return __builtin_amdgcn_mfma_f32_16x16x32_bf16(a, b, c, 0, 0, 0);
}
__device__ __forceinline__ void split2(float x, u16& h, u16& l) {
  h = f2bf(x);
  l = f2bf(x - bf2f(h));
}
__device__ __forceinline__ void split3(float x, u16& h, u16& m, u16& l) {
  h = f2bf(x);
  float r = x - bf2f(h);
  m = f2bf(r);
  l = f2bf(r - bf2f(m));
}

// ---------------- LayerNorm full output (fp32), one wave per row ----------------
__global__ __launch_bounds__(256) void ln_kernel(
    const float* __restrict__ x, const float* __restrict__ gamma,
    const float* __restrict__ beta, float* __restrict__ o, int rows, int C) {
  int wid = threadIdx.x >> 6, lane = threadIdx.x & 63;
  int row = blockIdx.x * 4 + wid;
  if (row >= rows) return;
  const float* xr = x + (size_t)row * C;
  float s = 0.f, s2 = 0.f;
  for (int c = lane; c < C; c += 64) { float v = xr[c]; s += v; s2 += v * v; }
  #pragma unroll
  for (int off = 32; off >= 1; off >>= 1) {
    s += __shfl_xor(s, off);
    s2 += __shfl_xor(s2, off);
  }
  float m = s / C;
  float var = s2 / C - m * m;
  float rs = rsqrtf(var + 1e-5f);
  float* orow = o + (size_t)row * C;
  for (int c = lane; c < C; c += 64) orow[c] = (xr[c] - m) * rs * gamma[c] + beta[c];
}

// ---------------- LayerNorm stats only: mrs[row] = {mean, rstd} ----------------
__global__ __launch_bounds__(256) void ln_stats_kernel(
    const float* __restrict__ x, float* __restrict__ mrs, int rows, int C) {
  int wid = threadIdx.x >> 6, lane = threadIdx.x & 63;
  int row = blockIdx.x * 4 + wid;
  if (row >= rows) return;
  const float* xr = x + (size_t)row * C;
  float s = 0.f, s2 = 0.f;
  for (int c = lane; c < C; c += 64) { float v = xr[c]; s += v; s2 += v * v; }
  #pragma unroll
  for (int off = 32; off >= 1; off >>= 1) {
    s += __shfl_xor(s, off);
    s2 += __shfl_xor(s2, off);
  }
  if (lane == 0) {
    float m = s / C;
    float var = s2 / C - m * m;
    mrs[row * 2] = m;
    mrs[row * 2 + 1] = rsqrtf(var + 1e-5f);
  }
}

// ------- Dense GEMM, fp32-accurate via 3-way bf16 split, reg-prefetch pipeline -------
// O = act((LN?)(relu?)(A) @ W^T + bias). A:[M,K], W:[N,K] fp32 row-major. 64x64 tile.
template <int LNA, int INRELU, int ACT, int ACC>
__global__ __launch_bounds__(256) void gemm_kernel(
    const float* __restrict__ A, const float* __restrict__ mrs,
    const float* __restrict__ lng, const float* __restrict__ lnb,
    const float* __restrict__ W, const float* __restrict__ bias,
    float* __restrict__ O, int M, int N, int K) {
  __shared__ __align__(16) u16 a_h[64][40], a_m[64][40], a_l[64][40];
  __shared__ __align__(16) u16 w_h[64][40], w_m[64][40], w_l[64][40];
  const int n0 = blockIdx.x * 64, m0 = blockIdx.y * 64;
  const int t = threadIdx.x;
  const int wid = t >> 6, lane = t & 63;
  const int cl = lane & 15, cg = lane >> 4;
  const int lrow = t >> 2, lq = t & 3;
  const float* ap = A + (size_t)(m0 + lrow) * K + lq * 8;
  const float* wp = W + (size_t)(n0 + lrow) * K + lq * 8;
  float rm = 0.f, rrs = 1.f;
  if (LNA) { rm = mrs[(m0 + lrow) * 2]; rrs = mrs[(m0 + lrow) * 2 + 1]; }
  float4 ra0, ra1, rw0, rw1, rg0, rg1, rb0, rb1;
  #define GLOADD(k0) do { \
    ra0 = ((const float4*)(ap + (k0)))[0]; ra1 = ((const float4*)(ap + (k0)))[1]; \
    rw0 = ((const float4*)(wp + (k0)))[0]; rw1 = ((const float4*)(wp + (k0)))[1]; \
    if (LNA) { \
      rg0 = ((const float4*)(lng + (k0) + lq * 8))[0]; rg1 = ((const float4*)(lng + (k0) + lq * 8))[1]; \
      rb0 = ((const float4*)(lnb + (k0) + lq * 8))[0]; rb1 = ((const float4*)(lnb + (k0) + lq * 8))[1]; \
    } } while (0)
  GLOADD(0);
  f32x4 acc[4] = {};
  for (int k0 = 0; k0 < K; k0 += 32) {
    {
      float av[8] = {ra0.x, ra0.y, ra0.z, ra0.w, ra1.x, ra1.y, ra1.z, ra1.w};
      if (LNA) {
        float gv[8] = {rg0.x, rg0.y, rg0.z, rg0.w, rg1.x, rg1.y, rg1.z, rg1.w};
        float bv[8] = {rb0.x, rb0.y, rb0.z, rb0.w, rb1.x, rb1.y, rb1.z, rb1.w};
        #pragma unroll
        for (int j = 0; j < 8; j++) av[j] = (av[j] - rm) * rrs * gv[j] + bv[j];
      }
      if (INRELU) {
        #pragma unroll
        for (int j = 0; j < 8; j++) av[j] = fmaxf(av[j], 0.f);
      }
      union { u16 s[8]; uint4 u; } ph, pm, pl;
      #pragma unroll
      for (int j = 0; j < 8; j++) split3(av[j], ph.s[j], pm.s[j], pl.s[j]);
      *(uint4*)&a_h[lrow][lq * 8] = ph.u;
      *(uint4*)&a_m[lrow][lq * 8] = pm.u;
      *(uint4*)&a_l[lrow][lq * 8] = pl.u;
      float wv[8] = {rw0.x, rw0.y, rw0.z, rw0.w, rw1.x, rw1.y, rw1.z, rw1.w};
      #pragma unroll
      for (int j = 0; j < 8; j++) split3(wv[j], ph.s[j], pm.s[j], pl.s[j]);
      *(uint4*)&w_h[lrow][lq * 8] = ph.u;
      *(uint4*)&w_m[lrow][lq * 8] = pm.u;
      *(uint4*)&w_l[lrow][lq * 8] = pl.u;
    }
    __syncthreads();
    if (k0 + 32 < K) GLOADD(k0 + 32);
    bf16x8 ah = *(const bf16x8*)&a_h[wid * 16 + cl][cg * 8];
    bf16x8 am = *(const bf16x8*)&a_m[wid * 16 + cl][cg * 8];
    bf16x8 al = *(const bf16x8*)&a_l[wid * 16 + cl][cg * 8];
    bf16x8 bh[4], bm_[4], bl[4];
    #pragma unroll
    for (int nt = 0; nt < 4; nt++) {
      bh[nt]  = *(const bf16x8*)&w_h[nt * 16 + cl][cg * 8];
      bm_[nt] = *(const bf16x8*)&w_m[nt * 16 + cl][cg * 8];
      bl[nt]  = *(const bf16x8*)&w_l[nt * 16 + cl][cg * 8];
    }
    #pragma unroll
    for (int nt = 0; nt < 4; nt++) acc[nt] = mfma_bf16(ah, bh[nt], acc[nt]);
    #pragma unroll
    for (int nt = 0; nt < 4; nt++) acc[nt] = mfma_bf16(ah, bm_[nt], acc[nt]);
    #pragma unroll
    for (int nt = 0; nt < 4; nt++) acc[nt] = mfma_bf16(am, bh[nt], acc[nt]);
    #pragma unroll
    for (int nt = 0; nt < 4; nt++) acc[nt] = mfma_bf16(ah, bl[nt], acc[nt]);
    #pragma unroll
    for (int nt = 0; nt < 4; nt++) acc[nt] = mfma_bf16(al, bh[nt], acc[nt]);
    #pragma unroll
    for (int nt = 0; nt < 4; nt++) acc[nt] = mfma_bf16(am, bm_[nt], acc[nt]);
    __syncthreads();
  }
  #undef GLOADD
  #pragma unroll
  for (int nt = 0; nt < 4; nt++) {
    #pragma unroll
    for (int i = 0; i < 4; i++) {
      int r = m0 + wid * 16 + cg * 4 + i;
      int c = n0 + nt * 16 + cl;
      float v = acc[nt][i];
      if (bias) v += bias[c];
      if (ACT == 1) v = fmaxf(v, 0.f);
      if (ACT == 2) v = 1.f / (1.f + __expf(-v));
      size_t oi = (size_t)r * N + c;
      if (ACC) O[oi] += v; else O[oi] = v;
    }
  }
}

// ------- Fused QKV + gate GEMM with LN-staged A. N=1536 (1152 qkv | 384 gate), K=384 -------
__global__ __launch_bounds__(256) void gemm_qkvg_kernel(
    const float* __restrict__ A, const float* __restrict__ mrs,
    const float* __restrict__ lng, const float* __restrict__ lnb,
    const float* __restrict__ wqkv, const float* __restrict__ wg,
    const float* __restrict__ bg, float* __restrict__ qkv, float* __restrict__ gbuf) {
  __shared__ __align__(16) u16 a_h[64][40], a_m[64][40], a_l[64][40];
  __shared__ __align__(16) u16 w_h[64][40], w_m[64][40], w_l[64][40];
  const int n0 = blockIdx.x * 64, m0 = blockIdx.y * 64;
  const bool isg = (n0 >= 1152);
  const float* W = isg ? (wg + (size_t)(n0 - 1152) * 384) : (wqkv + (size_t)n0 * 384);
  const int t = threadIdx.x;
  const int wid = t >> 6, lane = t & 63;
  const int cl = lane & 15, cg = lane >> 4;
  const int lrow = t >> 2, lq = t & 3;
  const float* ap = A + (size_t)(m0 + lrow) * 384 + lq * 8;
  const float* wp = W + (size_t)lrow * 384 + lq * 8;
  const float rm = mrs[(m0 + lrow) * 2];
  const float rrs = mrs[(m0 + lrow) * 2 + 1];
  float4 ra0, ra1, rw0, rw1, rg0, rg1, rb0, rb1;
  #define GLOADQ(k0) do { \
    ra0 = ((const float4*)(ap + (k0)))[0]; ra1 = ((const float4*)(ap + (k0)))[1]; \
    rw0 = ((const float4*)(wp + (k0)))[0]; rw1 = ((const float4*)(wp + (k0)))[1]; \
    rg0 = ((const float4*)(lng + (k0) + lq * 8))[0]; rg1 = ((const float4*)(lng + (k0) + lq * 8))[1]; \
    rb0 = ((const float4*)(lnb + (k0) + lq * 8))[0]; rb1 = ((const float4*)(lnb + (k0) + lq * 8))[1]; \
  } while (0)
  GLOADQ(0);
  f32x4 acc[4] = {};
  for (int k0 = 0; k0 < 384; k0 += 32) {
    {
      float av[8] = {ra0.x, ra0.y, ra0.z, ra0.w, ra1.x, ra1.y, ra1.z, ra1.w};
      float gv[8] = {rg0.x, rg0.y, rg0.z, rg0.w, rg1.x, rg1.y, rg1.z, rg1.w};
      float bv[8] = {rb0.x, rb0.y, rb0.z, rb0.w, rb1.x, rb1.y, rb1.z, rb1.w};
      union { u16 s[8]; uint4 u; } ph, pm, pl;
      #pragma unroll
      for (int j = 0; j < 8; j++) {
        float x = (av[j] - rm) * rrs * gv[j] + bv[j];
        split3(x, ph.s[j], pm.s[j], pl.s[j]);
      }
      *(uint4*)&a_h[lrow][lq * 8] = ph.u;
      *(uint4*)&a_m[lrow][lq * 8] = pm.u;
      *(uint4*)&a_l[lrow][lq * 8] = pl.u;
      float wv[8] = {rw0.x, rw0.y, rw0.z, rw0.w, rw1.x, rw1.y, rw1.z, rw1.w};
      #pragma unroll
      for (int j = 0; j < 8; j++) split3(wv[j], ph.s[j], pm.s[j], pl.s[j]);
      *(uint4*)&w_h[lrow][lq * 8] = ph.u;
      *(uint4*)&w_m[lrow][lq * 8] = pm.u;
      *(uint4*)&w_l[lrow][lq * 8] = pl.u;
    }
    __syncthreads();
    if (k0 + 32 < 384) GLOADQ(k0 + 32);
    bf16x8 ah = *(const bf16x8*)&a_h[wid * 16 + cl][cg * 8];
    bf16x8 am = *(const bf16x8*)&a_m[wid * 16 + cl][cg * 8];
    bf16x8 al = *(const bf16x8*)&a_l[wid * 16 + cl][cg * 8];
    bf16x8 bh[4], bm_[4], bl[4];
    #pragma unroll
    for (int nt = 0; nt < 4; nt++) {
      bh[nt]  = *(const bf16x8*)&w_h[nt * 16 + cl][cg * 8];
      bm_[nt] = *(const bf16x8*)&w_m[nt * 16 + cl][cg * 8];
      bl[nt]  = *(const bf16x8*)&w_l[nt * 16 + cl][cg * 8];
    }
    #pragma unroll
    for (int nt = 0; nt < 4; nt++) acc[nt] = mfma_bf16(ah, bh[nt], acc[nt]);
    #pragma unroll
    for (int nt = 0; nt < 4; nt++) acc[nt] = mfma_bf16(ah, bm_[nt], acc[nt]);
    #pragma unroll
    for (int nt = 0; nt < 4; nt++) acc[nt] = mfma_bf16(am, bh[nt], acc[nt]);
    #pragma unroll
    for (int nt = 0; nt < 4; nt++) acc[nt] = mfma_bf16(ah, bl[nt], acc[nt]);
    #pragma unroll
    for (int nt = 0; nt < 4; nt++) acc[nt] = mfma_bf16(al, bh[nt], acc[nt]);
    #pragma unroll
    for (int nt = 0; nt < 4; nt++) acc[nt] = mfma_bf16(am, bm_[nt], acc[nt]);
    __syncthreads();
  }
  #undef GLOADQ
  #pragma unroll
  for (int nt = 0; nt < 4; nt++) {
    #pragma unroll
    for (int i = 0; i < 4; i++) {
      int r = m0 + wid * 16 + cg * 4 + i;
      int c = n0 + nt * 16 + cl;
      float v = acc[nt][i];
      if (isg) {
        int cc = c - 1152;
        v = 1.f / (1.f + __expf(-(v + bg[cc])));
        gbuf[(size_t)r * 384 + cc] = v;
      } else {
        qkv[(size_t)r * 1152 + c] = v;
      }
    }
  }
}

// ------- Fused LN(z) + z@w_b^T -> bmat fp32; pipelined over 8 j-tiles per block -------
// grid: B*N = 1024 blocks (one per (b,i) row), 256 threads.
__global__ __launch_bounds__(256) void zbmat_kernel(
    const float* __restrict__ z, const float* __restrict__ gamma,
    const float* __restrict__ beta, const float* __restrict__ wb,
    const float* __restrict__ bbias, float* __restrict__ bm) {
  __shared__ __align__(16) u16 w_h[96][136], w_l[96][136];      // 52224 B
  __shared__ __align__(16) u16 a_h[2][64][136], a_l[2][64][136]; // 69632 B
  const int b = blockIdx.x >> 9;
  const int i = blockIdx.x & 511;
  const int t = threadIdx.x;
  // stage w_b split (once)
  for (int idx = t; idx < 96 * 128; idx += 256) {
    u16 h, l; split2(wb[idx], h, l);
    w_h[idx >> 7][idx & 127] = h;
    w_l[idx >> 7][idx & 127] = l;
  }
  const int r = t >> 2, q = t & 3;
  const int cq = q * 32;
  const float* zbase = z + ((size_t)(b * 512 + i) * 512) * 128 + (size_t)r * 128 + cq;
  // gamma/beta kept in registers for this thread's 32 channels
  float4 gv[8], bv[8];
  #pragma unroll
  for (int ii = 0; ii < 8; ii++) {
    gv[ii] = *(const float4*)(gamma + cq + ii * 4);
    bv[ii] = *(const float4*)(beta + cq + ii * 4);
  }
  const int wid = t >> 6, lane = t & 63;
  const int cl = lane & 15, cg = lane >> 4;
  const int arow = wid * 16 + cl;
  float bb[6];
  #pragma unroll
  for (int nt = 0; nt < 6; nt++) bb[nt] = bbias[nt * 16 + cl];
  float4 v[8];

  // LN + split + store to buffer `dst` from regs v[]
  auto ln_store = [&](int dst) {
    float s = 0.f, s2 = 0.f;
    #pragma unroll
    for (int ii = 0; ii < 8; ii++) {
      s += v[ii].x + v[ii].y + v[ii].z + v[ii].w;
      s2 += v[ii].x * v[ii].x + v[ii].y * v[ii].y + v[ii].z * v[ii].z + v[ii].w * v[ii].w;
    }
    s += __shfl_xor(s, 1); s2 += __shfl_xor(s2, 1);
    s += __shfl_xor(s, 2); s2 += __shfl_xor(s2, 2);
    const float m = s * (1.f / 128.f);
    const float var = s2 * (1.f / 128.f) - m * m;
    const float rs = rsqrtf(var + 1e-5f);
    #pragma unroll
    for (int st = 0; st < 2; st++) {
      float xv[16];
      #pragma unroll
      for (int w2 = 0; w2 < 4; w2++) {
        float4 x = v[st * 4 + w2];
        float4 g = gv[st * 4 + w2], be = bv[st * 4 + w2];
        xv[w2 * 4 + 0] = (x.x - m) * rs * g.x + be.x;
        xv[w2 * 4 + 1] = (x.y - m) * rs * g.y + be.y;
        xv[w2 * 4 + 2] = (x.z - m) * rs * g.z + be.z;
        xv[w2 * 4 + 3] = (x.w - m) * rs * g.w + be.w;
      }
      union { u16 s[8]; uint4 u; } ph, pl;
      #pragma unroll
      for (int j = 0; j < 8; j++) split2(xv[j], ph.s[j], pl.s[j]);
      *(uint4*)&a_h[dst][r][cq + st * 16] = ph.u;
      *(uint4*)&a_l[dst][r][cq + st * 16] = pl.u;
      #pragma unroll
      for (int j = 0; j < 8; j++) split2(xv[8 + j], ph.s[j], pl.s[j]);
      *(uint4*)&a_h[dst][r][cq + st * 16 + 8] = ph.u;
      *(uint4*)&a_l[dst][r][cq + st * 16 + 8] = pl.u;
    }
  };

  // prologue: tile 0
  #pragma unroll
  for (int ii = 0; ii < 8; ii++) v[ii] = ((const float4*)zbase)[ii];
  ln_store(0);
  __syncthreads();

  int cur = 0;
  for (int jt = 0; jt < 8; jt++) {
    // issue next-tile loads early (hidden under MFMA)
    if (jt < 7) {
      const float* src = zbase + (size_t)(jt + 1) * 64 * 128;
      #pragma unroll
      for (int ii = 0; ii < 8; ii++) v[ii] = ((const float4*)src)[ii];
    }
    f32x4 acc[6] = {};
    #pragma unroll
    for (int ks = 0; ks < 4; ks++) {
      bf16x8 ah = *(const bf16x8*)&a_h[cur][arow][ks * 32 + cg * 8];
      bf16x8 al = *(const bf16x8*)&a_l[cur][arow][ks * 32 + cg * 8];
      bf16x8 bh[6], bl[6];
      #pragma unroll
      for (int nt = 0; nt < 6; nt++) {
        bh[nt] = *(const bf16x8*)&w_h[nt * 16 + cl][ks * 32 + cg * 8];
        bl[nt] = *(const bf16x8*)&w_l[nt * 16 + cl][ks * 32 + cg * 8];
      }
      #pragma unroll
      for (int nt = 0; nt < 6; nt++) acc[nt] = mfma_bf16(ah, bh[nt], acc[nt]);
      #pragma unroll
      for (int nt = 0; nt < 6; nt++) acc[nt] = mfma_bf16(ah, bl[nt], acc[nt]);
      #pragma unroll
      for (int nt = 0; nt < 6; nt++) acc[nt] = mfma_bf16(al, bh[nt], acc[nt]);
    }
    // direct stores: 64B-coalesced groups per (cl, nt)
    #pragma unroll
    for (int nt = 0; nt < 6; nt++) {
      float4 o;
      o.x = acc[nt][0] + bb[nt]; o.y = acc[nt][1] + bb[nt];
      o.z = acc[nt][2] + bb[nt]; o.w = acc[nt][3] + bb[nt];
      int ch = nt * 16 + cl;
      *(float4*)&bm[((size_t)(b * 96 + ch) * 512 + i) * 512 + jt * 64 + wid * 16 + cg * 4] = o;
    }
    if (jt < 7) ln_store(cur ^ 1);
    __syncthreads();
    cur ^= 1;
  }
}

// ---------------- Fused attention (one layer), 2-way split precision ----------------
__global__ __launch_bounds__(128) void attn_kernel(
    const float* __restrict__ qkv, const float* __restrict__ bmat,
    const int* __restrict__ maskp, const float* __restrict__ gate,
    float* __restrict__ ybuf, int layer) {
  __shared__ __align__(16) u16 vT_h[32][520];
  __shared__ __align__(16) u16 vT_l[32][520];
  __shared__ __align__(16) u16 pst_h[2][16][32];
  __shared__ __align__(16) u16 pst_l[2][16][32];
  const int bid = blockIdx.x;
  const int qb = bid & 15;
  const int h = (bid >> 4) % 12;
  const int b = bid / 192;
  const int q0 = qb * 32;
  const int t = threadIdx.x;
  const int wid = t >> 6;
  const int lane = t & 63;
  const int cl = lane & 15, cg = lane >> 4;

  for (int idx = t; idx < 512 * 8; idx += 128) {
    int k = idx >> 3, c4 = (idx & 7) << 2;
    const float* vp = qkv + (size_t)(b * 512 + k) * 1152 + h * 96 + 64 + c4;
    float4 vv = *(const float4*)vp;
    float va[4] = {vv.x, vv.y, vv.z, vv.w};
    #pragma unroll
    for (int j = 0; j < 4; j++) {
      u16 hh, ll; split2(va[j], hh, ll);
      vT_h[c4 + j][k] = hh;
      vT_l[c4 + j][k] = ll;
    }
  }

  const int qrow = q0 + wid * 16 + cl;
  const float* qp = qkv + (size_t)(b * 512 + qrow) * 1152 + h * 96 + cg * 8;
  float4 qv0 = ((const float4*)qp)[0];
  float4 qv1 = ((const float4*)qp)[1];
  const float qs = 0.17677669529663687f;
  float qa[8] = {qv0.x, qv0.y, qv0.z, qv0.w, qv1.x, qv1.y, qv1.z, qv1.w};
  union { u16 s[8]; bf16x8 v; } qh, ql;
  #pragma unroll
  for (int j = 0; j < 8; j++) split2(qa[j] * qs, qh.s[j], ql.s[j]);

  __syncthreads();

  const f32x4 zero4 = {0.f, 0.f, 0.f, 0.f};
  f32x4 sc[32];
  #pragma unroll
  for (int nt = 0; nt < 32; nt++) {
    int kk = nt * 16 + cl;
    const float* kp = qkv + (size_t)(b * 512 + kk) * 1152 + h * 96 + 32 + cg * 8;
    float4 k0 = ((const float4*)kp)[0];
    float4 k1 = ((const float4*)kp)[1];
    float ka[8] = {k0.x, k0.y, k0.z, k0.w, k1.x, k1.y, k1.z, k1.w};
    union { u16 s[8]; bf16x8 v; } kh, kl;
    #pragma unroll
    for (int j = 0; j < 8; j++) split2(ka[j], kh.s[j], kl.s[j]);
    f32x4 a = mfma_bf16(qh.v, kh.v, zero4);
    a = mfma_bf16(qh.v, kl.v, a);
    a = mfma_bf16(ql.v, kh.v, a);
    sc[nt] = a;
  }

  const size_t bc = (size_t)(b * 96 + layer * 12 + h);
  #pragma unroll
  for (int nt = 0; nt < 32; nt++) {
    int kk = nt * 16 + cl;
    int mk = maskp[b * 512 + kk];
    #pragma unroll
    for (int i2 = 0; i2 < 4; i2++) {
      int qq = q0 + wid * 16 + cg * 4 + i2;
      float bias = bmat[(bc * 512 + qq) * 512 + kk];
      float vv = sc[nt][i2] + bias;
      sc[nt][i2] = (mk == 0) ? -1e9f : vv;
    }
  }

  float inv[4];
  #pragma unroll
  for (int i2 = 0; i2 < 4; i2++) {
    float mx = -3e38f;
    #pragma unroll
    for (int nt = 0; nt < 32; nt++) mx = fmaxf(mx, sc[nt][i2]);
    mx = fmaxf(mx, __shfl_xor(mx, 1));
    mx = fmaxf(mx, __shfl_xor(mx, 2));
    mx = fmaxf(mx, __shfl_xor(mx, 4));
    mx = fmaxf(mx, __shfl_xor(mx, 8));
    float ss = 0.f;
    #pragma unroll
    for (int nt = 0; nt < 32; nt++) {
      float p = __expf(sc[nt][i2] - mx);
      sc[nt][i2] = p;
      ss += p;
    }
    ss += __shfl_xor(ss, 1);
    ss += __shfl_xor(ss, 2);
    ss += __shfl_xor(ss, 4);
    ss += __shfl_xor(ss, 8);
    inv[i2] = 1.f / ss;
  }

  f32x4 yacc[2] = {};
  for (int ks = 0; ks < 16; ks++) {
    #pragma unroll
    for (int half = 0; half < 2; half++) {
      int nt = ks * 2 + half;
      #pragma unroll
      for (int i2 = 0; i2 < 4; i2++) {
        u16 hh, ll; split2(sc[nt][i2] * inv[i2], hh, ll);
        pst_h[wid][cg * 4 + i2][half * 16 + cl] = hh;
        pst_l[wid][cg * 4 + i2][half * 16 + cl] = ll;
      }
    }
    __syncthreads();
    bf16x8 ph = *(const bf16x8*)&pst_h[wid][cl][cg * 8];
    bf16x8 pl = *(const bf16x8*)&pst_l[wid][cl][cg * 8];
    #pragma unroll
    for (int nt2 = 0; nt2 < 2; nt2++) {
      bf16x8 vh = *(const bf16x8*)&vT_h[nt2 * 16 + cl][ks * 32 + cg * 8];
      bf16x8 vl = *(const bf16x8*)&vT_l[nt2 * 16 + cl][ks * 32 + cg * 8];
      yacc[nt2] = mfma_bf16(ph, vh, yacc[nt2]);
      yacc[nt2] = mfma_bf16(ph, vl, yacc[nt2]);
      yacc[nt2] = mfma_bf16(pl, vh, yacc[nt2]);
    }
    __syncthreads();
  }

  #pragma unroll
  for (int nt2 = 0; nt2 < 2; nt2++) {
    #pragma unroll
    for (int i2 = 0; i2 < 4; i2++) {
      int qq = q0 + wid * 16 + cg * 4 + i2;
      int c = nt2 * 16 + cl;
      size_t oi = (size_t)(b * 512 + qq) * 384 + h * 32 + c;
      ybuf[oi] = yacc[nt2][i2] * gate[oi];
    }
  }
}

// ---------------- small fp32 matvec: thread per (row, out) ----------------
template <int INRELU, int ACC>
__global__ __launch_bounds__(256) void matvec_kernel(
    const float* __restrict__ A, const float* __restrict__ W,
    const float* __restrict__ bias, float* __restrict__ O,
    int M, int N, int K, int Npad) {
  int idx = blockIdx.x * 256 + threadIdx.x;
  int r = idx / Npad, n = idx % Npad;
  if (r >= M || n >= N) return;
  const float* a = A + (size_t)r * K;
  const float* w = W + (size_t)n * K;
  float s = bias[n];
  for (int k = 0; k < K; k++) {
    float v = a[k];
    if (INRELU) v = fmaxf(v, 0.f);
    s += v * w[k];
  }
  size_t oi = (size_t)r * N + n;
  if (ACC) O[oi] += s; else O[oi] = s;
}

__device__ __forceinline__ void m3m(float* o, const float* a, const float* b) {
  #pragma unroll
  for (int i = 0; i < 3; i++)
    #pragma unroll
    for (int j = 0; j < 3; j++)
      o[i * 3 + j] = a[i * 3 + 0] * b[0 * 3 + j] + a[i * 3 + 1] * b[1 * 3 + j] + a[i * 3 + 2] * b[2 * 3 + j];
}
__device__ __forceinline__ void m3v(float* o, const float* a, const float* v) {
  #pragma unroll
  for (int i = 0; i < 3; i++)
    o[i] = a[i * 3 + 0] * v[0] + a[i * 3 + 1] * v[1] + a[i * 3 + 2] * v[2];
}

// ---------------- fused tail: normalize angles + make_rigid + frames + atoms ----------------
__global__ __launch_bounds__(256) void tail_kernel(
    const float* __restrict__ angraw, const float* __restrict__ bbbuf,
    const int* __restrict__ aatype, const float* __restrict__ deff,
    const int* __restrict__ gidx, const float* __restrict__ amask,
    const float* __restrict__ lit,
    float* __restrict__ o_ang, float* __restrict__ o_un,
    float* __restrict__ o_bb4, float* __restrict__ o_rg4, float* __restrict__ o_pred) {
  int idx = blockIdx.x * 256 + threadIdx.x;
  if (idx >= 1024) return;
  // --- angles ---
  float ang[14];
  #pragma unroll
  for (int a = 0; a < 7; a++) {
    float s0 = angraw[(idx * 7 + a) * 2], s1 = angraw[(idx * 7 + a) * 2 + 1];
    o_un[(idx * 7 + a) * 2] = s0; o_un[(idx * 7 + a) * 2 + 1] = s1;
    float d = sqrtf(fmaxf(s0 * s0 + s1 * s1, 1e-8f));
    ang[a * 2] = s0 / d; ang[a * 2 + 1] = s1 / d;
    o_ang[(idx * 7 + a) * 2] = ang[a * 2]; o_ang[(idx * 7 + a) * 2 + 1] = ang[a * 2 + 1];
  }
  // --- make_rigid ---
  const float* p = bbbuf + (size_t)idx * 9;
  float nx = p[0] - p[3], ny = p[1] - p[4], nz = p[2] - p[5];
  float cx = p[6] - p[3], cy = p[7] - p[4], cz = p[8] - p[5];
  const float eps = 1e-7f;
  float nrm = sqrtf(eps + cx * cx + cy * cy);
  float s1 = -cy / nrm, c1 = cx / nrm;
  float nrm2 = sqrtf(eps + cx * cx + cy * cy + cz * cz);
  float s2 = cz / nrm2, c2 = sqrtf(cx * cx + cy * cy) / nrm2;
  float Rc[9] = { c2 * c1, -c2 * s1, s2,
                  s1,      c1,       0.f,
                  -s2 * c1, s2 * s1, c2 };
  float n2y = Rc[3] * nx + Rc[4] * ny + Rc[5] * nz;
  float n2z = Rc[6] * nx + Rc[7] * ny + Rc[8] * nz;
  float nrm3 = sqrtf(eps + n2y * n2y + n2z * n2z);
  float sn = -n2z / nrm3, cn = n2y / nrm3;
  float Rm[9];
  Rm[0] = Rc[0]; Rm[1] = Rc[1]; Rm[2] = Rc[2];
  Rm[3] = cn * Rc[3] - sn * Rc[6];
  Rm[4] = cn * Rc[4] - sn * Rc[7];
  Rm[5] = cn * Rc[5] - sn * Rc[8];
  Rm[6] = sn * Rc[3] + cn * Rc[6];
  Rm[7] = sn * Rc[4] + cn * Rc[7];
  Rm[8] = sn * Rc[5] + cn * Rc[8];
  float Rb[9] = { Rm[0], Rm[3], Rm[6],
                  Rm[1], Rm[4], Rm[7],
                  Rm[2], Rm[5], Rm[8] };
  float tb[3] = { p[3] * 10.f, p[4] * 10.f, p[5] * 10.f };
  {
    float* o = o_bb4 + (size_t)idx * 16;
    o[0] = Rb[0]; o[1] = Rb[1]; o[2] = Rb[2]; o[3] = tb[0];
    o[4] = Rb[3]; o[5] = Rb[4]; o[6] = Rb[5]; o[7] = tb[1];
    o[8] = Rb[6]; o[9] = Rb[7]; o[10] = Rb[8]; o[11] = tb[2];
    o[12] = 0.f; o[13] = 0.f; o[14] = 0.f; o[15] = 1.f;
  }
  // --- frames ---
  int aa = aatype[idx];
  float Rf[8][9], tf[8][3];
  for (int g = 0; g < 8; g++) {
    const float* d4 = deff + ((size_t)aa * 8 + g) * 16;
    float sa = 0.f, ca = 1.f;
    if (g > 0) { sa = ang[(g - 1) * 2]; ca = ang[(g - 1) * 2 + 1]; }
    #pragma unroll
    for (int i = 0; i < 3; i++) {
      float d0 = d4[i * 4 + 0], d1 = d4[i * 4 + 1], d2 = d4[i * 4 + 2];
      Rf[g][i * 3 + 0] = d0;
      Rf[g][i * 3 + 1] = d1 * ca + d2 * sa;
      Rf[g][i * 3 + 2] = -d1 * sa + d2 * ca;
      tf[g][i] = d4[i * 4 + 3];
    }
  }
  float Rall[8][9], tall[8][3];
  for (int g = 0; g < 5; g++) {
    #pragma unroll
    for (int i = 0; i < 9; i++) Rall[g][i] = Rf[g][i];
    #pragma unroll
    for (int i = 0; i < 3; i++) tall[g][i] = tf[g][i];
  }
  m3m(Rall[5], Rf[4], Rf[5]); m3v(tall[5], Rf[4], tf[5]);
  tall[5][0] += tf[4][0]; tall[5][1] += tf[4][1]; tall[5][2] += tf[4][2];
  m3m(Rall[6], Rall[5], Rf[6]); m3v(tall[6], Rall[5], tf[6]);
  tall[6][0] += tall[5][0]; tall[6][1] += tall[5][1]; tall[6][2] += tall[5][2];
  m3m(Rall[7], Rall[6], Rf[7]); m3v(tall[7], Rall[6], tf[7]);
  tall[7][0] += tall[6][0]; tall[7][1] += tall[6][1]; tall[7][2] += tall[6][2];
  float RG[8][9], TG[8][3];
  for (int g = 0; g < 8; g++) {
    m3m(RG[g], Rb, Rall[g]);
    m3v(TG[g], Rb, tall[g]);
    TG[g][0] += tb[0]; TG[g][1] += tb[1]; TG[g][2] += tb[2];
    float* o = o_rg4 + ((size_t)idx * 8 + g) * 16;
    o[0] = RG[g][0]; o[1] = RG[g][1]; o[2] = RG[g][2]; o[3] = TG[g][0];
    o[4] = RG[g][3]; o[5] = RG[g][4]; o[6] = RG[g][5]; o[7] = TG[g][1];
    o[8] = RG[g][6]; o[9] = RG[g][7]; o[10] = RG[g][8]; o[11] = TG[g][2];
    o[12] = 0.f; o[13] = 0.f; o[14] = 0.f; o[15] = 1.f;
  }
  for (int a = 0; a < 14; a++) {
    int gi = gidx[aa * 14 + a];
    const float* lp = lit + ((size_t)aa * 14 + a) * 3;
    float mk = amask[aa * 14 + a];
    float px = RG[gi][0] * lp[0] + RG[gi][1] * lp[1] + RG[gi][2] * lp[2] + TG[gi][0];
    float py = RG[gi][3] * lp[0] + RG[gi][4] * lp[1] + RG[gi][5] * lp[2] + TG[gi][1];
    float pz = RG[gi][6] * lp[0] + RG[gi][7] * lp[1] + RG[gi][8] * lp[2] + TG[gi][2];
    float* op = o_pred + ((size_t)idx * 14 + a) * 3;
    op[0] = px * mk; op[1] = py * mk; op[2] = pz * mk;
  }
}

__global__ __launch_bounds__(256) void copy_kernel(const float4* __restrict__ s, float4* __restrict__ d) {
  int i = blockIdx.x * 256 + threadIdx.x;
  d[i] = s[i];
}

extern "C" void kernel_launch(void* const* d_in, const int* in_sizes, int n_in,
                              void* d_out, int out_size, void* d_ws, size_t ws_size,
                              hipStream_t stream) {
  (void)in_sizes; (void)n_in; (void)out_size; (void)ws_size;
  const float* s_in    = (const float*)d_in[0];
  const float* z_in    = (const float*)d_in[1];
  const int*   aatype  = (const int*)d_in[2];
  const int*   maskp   = (const int*)d_in[3];
  const float* ln_s_g  = (const float*)d_in[4];
  const float* ln_s_b  = (const float*)d_in[5];
  const float* ln_z_g  = (const float*)d_in[6];
  const float* ln_z_b  = (const float*)d_in[7];
  const float* w_in    = (const float*)d_in[8];
  const float* b_in    = (const float*)d_in[9];
  const float* w_b     = (const float*)d_in[10];
  const float* b_b     = (const float*)d_in[11];
  const float* attn_ln_g = (const float*)d_in[12];
  const float* attn_ln_b = (const float*)d_in[13];
  const float* attn_wqkv = (const float*)d_in[14];
  const float* attn_wo   = (const float*)d_in[15];
  const float* attn_bo   = (const float*)d_in[16];
  const float* attn_wg   = (const float*)d_in[17];
  const float* attn_bg   = (const float*)d_in[18];
  const float* tr_ln_g   = (const float*)d_in[19];
  const float* tr_ln_b   = (const float*)d_in[20];
  const float* tr_w1     = (const float*)d_in[21];
  const float* tr_b1     = (const float*)d_in[22];
  const float* tr_w2     = (const float*)d_in[23];
  const float* tr_b2     = (const float*)d_in[24];
  const float* w_bb      = (const float*)d_in[25];
  const float* b_bb      = (const float*)d_in[26];
  const float* ar_win    = (const float*)d_in[27];
  const float* ar_bin    = (const float*)d_in[28];
  const float* ar_winit  = (const float*)d_in[29];
  const float* ar_binit  = (const float*)d_in[30];
  const float* ar_w1     = (const float*)d_in[31];
  const float* ar_b1     = (const float*)d_in[32];
  const float* ar_w2     = (const float*)d_in[33];
  const float* ar_b2     = (const float*)d_in[34];
  const float* ar_wout   = (const float*)d_in[35];
  const float* ar_bout   = (const float*)d_in[36];
  const float* def_frames= (const float*)d_in[37];
  const int*   group_idx = (const int*)d_in[38];
  const float* atom_mask = (const float*)d_in[39];
  const float* lit_pos   = (const float*)d_in[40];

  char* p = (char*)d_ws;
  float* bmat   = (float*)p;          p += 201326592;
  float* s_init = (float*)p;          p += 1572864;
  float* s_cur  = (float*)p;          p += 1572864;
  float* qkv    = (float*)p;          p += 4718592;
  float* gbuf   = (float*)p;          p += 1572864;
  float* ybuf   = (float*)p;          p += 1572864;
  float* h1buf  = (float*)p;          p += 1572864;
  float* abuf   = (float*)p;          p += 524288;
  float* htmp   = (float*)p;          p += 524288;
  float* angraw = (float*)p;          p += 57344;
  float* bbbuf  = (float*)p;          p += 36864;
  float* mrs    = (float*)p;          p += 8192;

  float* out    = (float*)d_out;
  float* o_ang  = out;
  float* o_un   = out + 14336;
  float* o_bb4  = out + 28672;
  float* o_rg4  = out + 45056;
  float* o_pred = out + 176128;
  float* o_s    = out + 219136;

  // s_init = LN(s)
  ln_kernel<<<256, 256, 0, stream>>>(s_in, ln_s_g, ln_s_b, s_init, 1024, 384);
  // s = lin(s_init, w_in, b_in)
  gemm_kernel<0, 0, 0, 0><<<dim3(6, 16), 256, 0, stream>>>(
      s_init, nullptr, nullptr, nullptr, w_in, b_in, s_cur, 1024, 384, 384);
  // bmat from z (fp32)
  zbmat_kernel<<<1024, 256, 0, stream>>>(z_in, ln_z_g, ln_z_b, w_b, b_b, bmat);

  for (int l = 0; l < 8; ++l) {
    ln_stats_kernel<<<256, 256, 0, stream>>>(s_cur, mrs, 1024, 384);
    gemm_qkvg_kernel<<<dim3(24, 16), 256, 0, stream>>>(
        s_cur, mrs, attn_ln_g + l * 384, attn_ln_b + l * 384,
        attn_wqkv + (size_t)l * 442368, attn_wg + (size_t)l * 147456,
        attn_bg + l * 384, qkv, gbuf);
    attn_kernel<<<384, 128, 0, stream>>>(qkv, bmat, maskp, gbuf, ybuf, l);
    gemm_kernel<0, 0, 0, 1><<<dim3(6, 16), 256, 0, stream>>>(
        ybuf, nullptr, nullptr, nullptr, attn_wo + (size_t)l * 147456,
        attn_bo + l * 384, s_cur, 1024, 384, 384);
    ln_stats_kernel<<<256, 256, 0, stream>>>(s_cur, mrs, 1024, 384);
    gemm_kernel<1, 0, 1, 0><<<dim3(6, 16), 256, 0, stream>>>(
        s_cur, mrs, tr_ln_g + l * 384, tr_ln_b + l * 384,
        tr_w1 + (size_t)l * 147456, tr_b1 + l * 384, h1buf, 1024, 384, 384);
    gemm_kernel<0, 0, 0, 1><<<dim3(6, 16), 256, 0, stream>>>(
        h1buf, nullptr, nullptr, nullptr, tr_w2 + (size_t)l * 147456,
        tr_b2 + l * 384, s_cur, 1024, 384, 384);
  }

  // angle resnet (3-split MFMA gemms)
  gemm_kernel<0, 1, 0, 0><<<dim3(2, 16), 256, 0, stream>>>(
      s_cur, nullptr, nullptr, nullptr, ar_win, ar_bin, abuf, 1024, 128, 384);
  gemm_kernel<0, 1, 0, 1><<<dim3(2, 16), 256, 0, stream>>>(
      s_init, nullptr, nullptr, nullptr, ar_winit, ar_binit, abuf, 1024, 128, 384);
  for (int j = 0; j < 2; ++j) {
    gemm_kernel<0, 1, 0, 0><<<dim3(2, 16), 256, 0, stream>>>(
        abuf, nullptr, nullptr, nullptr, ar_w1 + j * 16384, ar_b1 + j * 128, htmp, 1024, 128, 128);
    gemm_kernel<0, 1, 0, 1><<<dim3(2, 16), 256, 0, stream>>>(
        htmp, nullptr, nullptr, nullptr, ar_w2 + j * 16384, ar_b2 + j * 128, abuf, 1024, 128, 128);
  }
  matvec_kernel<1, 0><<<64, 256, 0, stream>>>(abuf, ar_wout, ar_bout, angraw, 1024, 14, 128, 16);

  // backbone + tail
  matvec_kernel<0, 0><<<64, 256, 0, stream>>>(s_cur, w_bb, b_bb, bbbuf, 1024, 9, 384, 16);
  tail_kernel<<<4, 256, 0, stream>>>(angraw, bbbuf, aatype, def_frames, group_idx,
                                     atom_mask, lit_pos, o_ang, o_un, o_bb4, o_rg4, o_pred);
  copy_kernel<<<384, 256, 0, stream>>>((const float4*)s_cur, (float4*)o_s);
}